// Round 9
// baseline (1533.223 us; speedup 1.0000x reference)
//
#include <hip/hip_runtime.h>
#include <hip/hip_fp16.h>
#include <cstdint>

#define T_LEN 128
#define DA    16
#define DZ    32
#define HH    128

__device__ __forceinline__ float sigm(float x){ return 1.0f/(1.0f + __expf(-x)); }
__device__ __forceinline__ float tanh_f(float x){ return 1.0f - 2.0f/(__expf(2.0f*x)+1.0f); }
__device__ __forceinline__ float dot4(float4 a, float4 b){ return a.x*b.x + a.y*b.y + a.z*b.z + a.w*b.w; }

typedef _Float16 h2v __attribute__((ext_vector_type(2)));
__device__ __forceinline__ float fdot2(uint32_t w, uint32_t h, float acc){
  union{uint32_t u; h2v v;} a, b; a.u = w; b.u = h;
  return __builtin_amdgcn_fdot2(a.v, b.v, acc, false);
}
__device__ __forceinline__ uint32_t packh2(float x, float y){
  return (uint32_t)__half_as_ushort(__float2half(x)) |
         ((uint32_t)__half_as_ushort(__float2half(y)) << 16);
}
__device__ __forceinline__ uint32_t rlane(uint32_t v, int l){
  return (uint32_t)__builtin_amdgcn_readlane((int)v, l);
}

// ws layout (32-bit words):
//   [0,4096)         Wih0h fp16-pairs: word idx (m*512+g)*4+q, m<2, q<4 -> w[g][8m+2q..+1]
//   [4096,36864)     Whh0h: m<16
//   [36864,69632)    Wih1h: m<16
//   [69632,102400)   Whh1h: m<16
//   [102400,102912)  b0 = bih0+bhh0 (f32)
//   [102912,103424)  b1 = bih1+bhh1 (f32)
//   [103424,300032)  alpha (512,128,3) f32

__global__ void prep_kernel(const float* __restrict__ Wih0, const float* __restrict__ Whh0,
                            const float* __restrict__ bih0, const float* __restrict__ bhh0,
                            const float* __restrict__ Wih1, const float* __restrict__ Whh1,
                            const float* __restrict__ bih1, const float* __restrict__ bhh1,
                            uint32_t* __restrict__ ws) {
  int idx = blockIdx.x*256 + threadIdx.x;
  if (idx < 4096) {
    int q = idx & 3, g = (idx >> 2) & 511, m = idx >> 11;
    int k0 = 8*m + 2*q;
    ws[idx] = packh2(Wih0[g*DA + k0], Wih0[g*DA + k0 + 1]);
  } else if (idx < 36864) {
    int f = idx - 4096;
    int q = f & 3, g = (f >> 2) & 511, m = f >> 11;
    int k0 = 8*m + 2*q;
    ws[idx] = packh2(Whh0[g*HH + k0], Whh0[g*HH + k0 + 1]);
  } else if (idx < 69632) {
    int f = idx - 36864;
    int q = f & 3, g = (f >> 2) & 511, m = f >> 11;
    int k0 = 8*m + 2*q;
    ws[idx] = packh2(Wih1[g*HH + k0], Wih1[g*HH + k0 + 1]);
  } else if (idx < 102400) {
    int f = idx - 69632;
    int q = f & 3, g = (f >> 2) & 511, m = f >> 11;
    int k0 = 8*m + 2*q;
    ws[idx] = packh2(Whh1[g*HH + k0], Whh1[g*HH + k0 + 1]);
  } else if (idx < 102912) {
    int j = idx - 102400;
    ((float*)ws)[idx] = bih0[j] + bhh0[j];
  } else if (idx < 103424) {
    int j = idx - 102912;
    ((float*)ws)[idx] = bih1[j] + bhh1[j];
  }
}

// Persistent 2-layer LSTM v8: register weights + READLANE h-broadcast.
// One block = one batch row, 512 threads, thread g = gate g, weights in VGPRs.
// h vectors are loaded once per step per wave with a single ds_read_b32
// (lane l <- packed word l) and distributed via v_readlane -> SGPR operand of
// v_dot2_f32_f16. DS insts/wave/step: ~6 (was 50 b128 broadcasts = the round-8
// LDS-pipe bottleneck, 400 DS insts/step/CU).
// Barrier hazards: gates written (all) -> B1 -> act0 reads gates, writes sh0h
// -> B2 -> all load h0reg, write gates -> B3 -> act1 reads gates, writes sh1h
// -> B4 -> all load h1reg; head (wave0 regs only). Next gates write is after
// B4; next sh0h/sh1h writes are behind B1..B3 of t+1. No 5th barrier needed.
__global__ __launch_bounds__(512, 2) void lstm_kernel(
    const float* __restrict__ a, const float* __restrict__ a0,
    const uint32_t* __restrict__ wsw, const float* __restrict__ Wlin,
    const float* __restrict__ blin, float* __restrict__ alpha_out) {
  const uint4* Wih0p = (const uint4*)(wsw);
  const uint4* Whh0p = (const uint4*)(wsw + 4096);
  const uint4* Wih1p = (const uint4*)(wsw + 36864);
  const uint4* Whh1p = (const uint4*)(wsw + 69632);
  const float* b0v = (const float*)(wsw + 102400);
  const float* b1v = (const float*)(wsw + 102912);

  __shared__ __align__(16) uint32_t sxh[T_LEN][8];   // x packed half2 (this row)
  __shared__ __align__(16) uint32_t sh0h[64];        // h0 packed half2
  __shared__ __align__(16) uint32_t sh1h[64];        // h1 packed half2
  __shared__ float gates[4*HH];

  int tid = threadIdx.x;
  int lane = tid & 63;
  int b = blockIdx.x;

  // ---- one-time: weights into registers ----
  uint4 wi0[2], wh0[16], wi1[16], wh1[16];
  #pragma unroll
  for (int m = 0; m < 2; ++m)  wi0[m] = Wih0p[m*512 + tid];
  #pragma unroll
  for (int m = 0; m < 16; ++m) wh0[m] = Whh0p[m*512 + tid];
  #pragma unroll
  for (int m = 0; m < 16; ++m) wi1[m] = Wih1p[m*512 + tid];
  #pragma unroll
  for (int m = 0; m < 16; ++m) wh1[m] = Whh1p[m*512 + tid];
  float bi0 = b0v[tid], bi1 = b1v[tid];

  for (int i = tid; i < T_LEN*8; i += 512) {
    int t = i >> 3, p = i & 7;
    float x0, x1;
    if (t == 0) { x0 = a0[2*p]; x1 = a0[2*p+1]; }
    else {
      const float* src = a + ((size_t)b*T_LEN + (t-1))*DA;
      x0 = src[2*p]; x1 = src[2*p+1];
    }
    sxh[t][p] = packh2(x0, x1);
  }
  // wave-0 head weights (Wlin columns for cells 2*lane, 2*lane+1)
  float wl00 = 0.f, wl01 = 0.f, wl10 = 0.f, wl11 = 0.f, wl20 = 0.f, wl21 = 0.f;
  if (tid < 64) {
    wl00 = Wlin[0*HH + 2*lane]; wl01 = Wlin[0*HH + 2*lane+1];
    wl10 = Wlin[1*HH + 2*lane]; wl11 = Wlin[1*HH + 2*lane+1];
    wl20 = Wlin[2*HH + 2*lane]; wl21 = Wlin[2*HH + 2*lane+1];
  }
  float bl0 = blin[0], bl1 = blin[1], bl2 = blin[2];
  // cell states in wave-0 registers (cells 2*lane, 2*lane+1)
  float c00 = 0.f, c01 = 0.f, c10 = 0.f, c11 = 0.f;
  uint32_t h0reg = 0u, h1reg = 0u;   // packed h word `lane` of previous step
  __syncthreads();

  #pragma unroll 1
  for (int t = 0; t < T_LEN; ++t) {
    // ---- layer 0 gates: g = tid; h0(t-1) via readlane of h0reg ----
    {
      float ga = bi0, gb = 0.f, gc = 0.f, gd = 0.f;
      uint4 x0 = *(const uint4*)&sxh[t][0];
      uint4 x1 = *(const uint4*)&sxh[t][4];
      ga = fdot2(wi0[0].x, x0.x, ga); gb = fdot2(wi0[0].y, x0.y, gb);
      gc = fdot2(wi0[0].z, x0.z, gc); gd = fdot2(wi0[0].w, x0.w, gd);
      ga = fdot2(wi0[1].x, x1.x, ga); gb = fdot2(wi0[1].y, x1.y, gb);
      gc = fdot2(wi0[1].z, x1.z, gc); gd = fdot2(wi0[1].w, x1.w, gd);
      #pragma unroll
      for (int m = 0; m < 16; ++m) {
        ga = fdot2(wh0[m].x, rlane(h0reg, 4*m+0), ga);
        gb = fdot2(wh0[m].y, rlane(h0reg, 4*m+1), gb);
        gc = fdot2(wh0[m].z, rlane(h0reg, 4*m+2), gc);
        gd = fdot2(wh0[m].w, rlane(h0reg, 4*m+3), gd);
      }
      gates[tid] = (ga + gb) + (gc + gd);
    }
    __syncthreads();                                   // B1
    if (tid < 64) {
      int j0 = 2*lane, j1 = j0 + 1;
      float i0 = gates[j0],      f0 = gates[j0+HH],
            q0 = gates[j0+2*HH], o0 = gates[j0+3*HH];
      c00 = sigm(f0)*c00 + sigm(i0)*tanh_f(q0);
      float hv0 = sigm(o0)*tanh_f(c00);
      float i1 = gates[j1],      f1 = gates[j1+HH],
            q1 = gates[j1+2*HH], o1 = gates[j1+3*HH];
      c01 = sigm(f1)*c01 + sigm(i1)*tanh_f(q1);
      float hv1 = sigm(o1)*tanh_f(c01);
      sh0h[lane] = packh2(hv0, hv1);
    }
    __syncthreads();                                   // B2
    h0reg = sh0h[lane];                                // h0(t), used L1 now and L0(t+1)
    // ---- layer 1 gates ----
    {
      float ga = bi1, gb = 0.f, gc = 0.f, gd = 0.f;
      #pragma unroll
      for (int m = 0; m < 16; ++m) {
        ga = fdot2(wi1[m].x, rlane(h0reg, 4*m+0), ga);
        gb = fdot2(wi1[m].y, rlane(h0reg, 4*m+1), gb);
        gc = fdot2(wi1[m].z, rlane(h0reg, 4*m+2), gc);
        gd = fdot2(wi1[m].w, rlane(h0reg, 4*m+3), gd);
      }
      #pragma unroll
      for (int m = 0; m < 16; ++m) {
        ga = fdot2(wh1[m].x, rlane(h1reg, 4*m+0), ga);
        gb = fdot2(wh1[m].y, rlane(h1reg, 4*m+1), gb);
        gc = fdot2(wh1[m].z, rlane(h1reg, 4*m+2), gc);
        gd = fdot2(wh1[m].w, rlane(h1reg, 4*m+3), gd);
      }
      gates[tid] = (ga + gb) + (gc + gd);
    }
    __syncthreads();                                   // B3
    float hv0 = 0.f, hv1 = 0.f;
    if (tid < 64) {
      int j0 = 2*lane, j1 = j0 + 1;
      float i0 = gates[j0],      f0 = gates[j0+HH],
            q0 = gates[j0+2*HH], o0 = gates[j0+3*HH];
      c10 = sigm(f0)*c10 + sigm(i0)*tanh_f(q0);
      hv0 = sigm(o0)*tanh_f(c10);
      float i1 = gates[j1],      f1 = gates[j1+HH],
            q1 = gates[j1+2*HH], o1 = gates[j1+3*HH];
      c11 = sigm(f1)*c11 + sigm(i1)*tanh_f(q1);
      hv1 = sigm(o1)*tanh_f(c11);
      sh1h[lane] = packh2(hv0, hv1);
    }
    __syncthreads();                                   // B4
    h1reg = sh1h[lane];                                // h1(t), used wh1 at t+1
    // ---- head: softmax(h1 @ Wlin^T + blin), wave 0, register-only ----
    if (tid < 64) {
      float p0 = hv0*wl00 + hv1*wl01;
      float p1 = hv0*wl10 + hv1*wl11;
      float p2 = hv0*wl20 + hv1*wl21;
      #pragma unroll
      for (int off = 32; off > 0; off >>= 1) {
        p0 += __shfl_down(p0, off); p1 += __shfl_down(p1, off); p2 += __shfl_down(p2, off);
      }
      if (lane == 0) {
        float l0 = p0 + bl0, l1 = p1 + bl1, l2 = p2 + bl2;
        float mx = fmaxf(l0, fmaxf(l1, l2));
        float e0=__expf(l0-mx), e1=__expf(l1-mx), e2=__expf(l2-mx);
        float inv = 1.0f/(e0+e1+e2);
        float* dst = alpha_out + ((size_t)b*T_LEN + t)*3;
        dst[0]=e0*inv; dst[1]=e1*inv; dst[2]=e2*inv;
      }
    }
  }
}

// Kalman scan v4 (unchanged from round 7/8): conflict-free k-row matmuls,
// register prefetch of A/C, wave-synchronous Gauss-Jordan.
__global__ __launch_bounds__(256) void kalman_kernel(
    const float* __restrict__ a, const float* __restrict__ A,
    const float* __restrict__ C, const float* __restrict__ alpha,
    float* __restrict__ out) {
  __shared__ __align__(16) float Sg[DZ][36];
  __shared__ __align__(16) float Am[DZ][36];
  __shared__ __align__(16) float AmT[DZ][36];
  __shared__ __align__(16) float Cm[DA][36];
  __shared__ __align__(16) float Nn[DZ][20];
  __shared__ __align__(16) float NnT[DA][36];
  __shared__ __align__(16) float Aug[DA][36];
  __shared__ __align__(16) float Kg[DZ][20];
  __shared__ __align__(16) float Sp2[DZ][36];
  __shared__ __align__(16) float T2m[DZ][36];
  __shared__ __align__(16) float sa[T_LEN][DA];
  __shared__ float salpha[T_LEN*3];
  __shared__ __align__(16) float muv[DZ], mun[DZ], rv[DA];

  int tid = threadIdx.x;
  int b = blockIdx.x;

  for (int e = tid; e < T_LEN*DA; e += 256) (&sa[0][0])[e] = a[(size_t)b*T_LEN*DA + e];
  for (int e = tid; e < T_LEN*3; e += 256) salpha[e] = alpha[(size_t)b*T_LEN*3 + e];
  for (int e = tid; e < DZ*36; e += 256) (&Sg[0][0])[e] = 0.0f;
  __syncthreads();
  if (tid < DZ) { Sg[tid][tid] = 1.0f; muv[tid] = 0.0f; }

  const int i8 = tid >> 3, jA = tid & 7, jB = jA + 8, j4m = jA * 4;
  const int i16 = tid >> 4, j16 = tid & 15;
  const int iR = tid & 31, j4r = (tid >> 5) * 4;

  const float4* A4 = (const float4*)A;
  const float4* C4 = (const float4*)C;
  float4 pA0 = A4[(0*T_LEN + 1)*256 + tid];
  float4 pA1 = A4[(1*T_LEN + 1)*256 + tid];
  float4 pA2 = A4[(2*T_LEN + 1)*256 + tid];
  float4 pC0, pC1, pC2;
  if (tid < 128) {
    pC0 = C4[(0*T_LEN + 0)*128 + tid];
    pC1 = C4[(1*T_LEN + 0)*128 + tid];
    pC2 = C4[(2*T_LEN + 0)*128 + tid];
  }
  __syncthreads();

  #pragma unroll 1
  for (int t = 0; t < T_LEN; ++t) {
    int ta = (t < T_LEN-1) ? t+1 : t;
    float b10 = salpha[ta*3+0], b11 = salpha[ta*3+1], b12 = salpha[ta*3+2];
    float b00 = salpha[t*3+0],  b01 = salpha[t*3+1],  b02 = salpha[t*3+2];

    {
      float4 v;
      v.x = b10*pA0.x + b11*pA1.x + b12*pA2.x;
      v.y = b10*pA0.y + b11*pA1.y + b12*pA2.y;
      v.z = b10*pA0.z + b11*pA1.z + b12*pA2.z;
      v.w = b10*pA0.w + b11*pA1.w + b12*pA2.w;
      *(float4*)&Am[i8][j4m] = v;
      AmT[j4m+0][i8] = v.x; AmT[j4m+1][i8] = v.y;
      AmT[j4m+2][i8] = v.z; AmT[j4m+3][i8] = v.w;
      if (tid < 128) {
        float4 c;
        c.x = b00*pC0.x + b01*pC1.x + b02*pC2.x;
        c.y = b00*pC0.y + b01*pC1.y + b02*pC2.y;
        c.z = b00*pC0.z + b01*pC1.z + b02*pC2.z;
        c.w = b00*pC0.w + b01*pC1.w + b02*pC2.w;
        *(float4*)&Cm[tid>>3][(tid&7)*4] = c;
      }
      int tn  = (t+1 < T_LEN) ? t+1 : T_LEN-1;
      int tan = (tn < T_LEN-1) ? tn+1 : tn;
      pA0 = A4[(0*T_LEN + tan)*256 + tid];
      pA1 = A4[(1*T_LEN + tan)*256 + tid];
      pA2 = A4[(2*T_LEN + tan)*256 + tid];
      if (tid < 128) {
        pC0 = C4[(0*T_LEN + tn)*128 + tid];
        pC1 = C4[(1*T_LEN + tn)*128 + tid];
        pC2 = C4[(2*T_LEN + tn)*128 + tid];
      }
    }
    __syncthreads();

    {
      float accA = 0.0f, accB = 0.0f;
      #pragma unroll
      for (int k4 = 0; k4 < 8; ++k4) {
        float4 s  = *(const float4*)&Sg[i8][k4*4];
        float4 cA = *(const float4*)&Cm[jA][k4*4];
        float4 cB = *(const float4*)&Cm[jB][k4*4];
        accA += dot4(s,cA); accB += dot4(s,cB);
      }
      Nn[i8][jA] = accA; Nn[i8][jB] = accB;
      NnT[jA][i8] = accA; NnT[jB][i8] = accB;
      if (tid < DA) {
        float acc = sa[t][tid];
        #pragma unroll
        for (int k4 = 0; k4 < 8; ++k4)
          acc -= dot4(*(const float4*)&Cm[tid][k4*4], *(const float4*)&muv[k4*4]);
        rv[tid] = acc;
      }
    }
    __syncthreads();

    {
      float acc = 0.0f;
      #pragma unroll
      for (int k4 = 0; k4 < 8; ++k4) {
        float4 c = *(const float4*)&Cm[i16][k4*4];
        float4 n = *(const float4*)&NnT[j16][k4*4];
        acc += dot4(c,n);
      }
      Aug[i16][j16] = acc + ((i16 == j16) ? 0.01f : 0.0f);
      Aug[i16][16 + j16] = (i16 == j16) ? 1.0f : 0.0f;
    }
    __syncthreads();

    if (tid < 64) {
      int lane = tid;
      int r = lane >> 2, cb = lane & 3;
      float v[8];
      #pragma unroll
      for (int j = 0; j < 8; ++j) v[j] = Aug[r][cb*8 + j];
      #pragma unroll
      for (int p = 0; p < DA; ++p) {
        float App = __shfl(v[p & 7], (p << 2) | (p >> 3), 64);
        float f   = __shfl(v[p & 7], (lane & 60) | (p >> 3), 64);
        float prow[8];
        #pragma unroll
        for (int j = 0; j < 8; ++j) prow[j] = __shfl(v[j], (p << 2) | cb, 64);
        float pinv = 1.0f / App;
        if (r == p) {
          #pragma unroll
          for (int j = 0; j < 8; ++j) v[j] *= pinv;
        } else {
          float fp = f * pinv;
          #pragma unroll
          for (int j = 0; j < 8; ++j) v[j] -= fp * prow[j];
        }
      }
      if (cb >= 2) {
        #pragma unroll
        for (int j = 0; j < 8; ++j) Aug[r][cb*8 + j] = v[j];
      }
    }
    __syncthreads();

    {
      float accA = 0.0f, accB = 0.0f;
      #pragma unroll
      for (int k4 = 0; k4 < 4; ++k4) {
        float4 n  = *(const float4*)&Nn[i8][k4*4];
        float4 sA = *(const float4*)&Aug[jA][16 + k4*4];
        float4 sB = *(const float4*)&Aug[jB][16 + k4*4];
        accA += dot4(n,sA); accB += dot4(n,sB);
      }
      Kg[i8][jA] = accA; Kg[i8][jB] = accB;
    }
    __syncthreads();

    if (tid < DZ) {
      float m = muv[tid];
      #pragma unroll
      for (int k4 = 0; k4 < 4; ++k4)
        m += dot4(*(const float4*)&Kg[tid][k4*4], *(const float4*)&rv[k4*4]);
      mun[tid] = m;
      out[((size_t)b*T_LEN + t)*DZ + tid] = m;
    }
    {
      float4 acc = *(const float4*)&Sg[iR][j4r];
      #pragma unroll
      for (int k4 = 0; k4 < 4; ++k4) {
        float4 kv = *(const float4*)&Kg[iR][k4*4];
        float4 n0 = *(const float4*)&NnT[4*k4+0][j4r];
        float4 n1 = *(const float4*)&NnT[4*k4+1][j4r];
        float4 n2 = *(const float4*)&NnT[4*k4+2][j4r];
        float4 n3 = *(const float4*)&NnT[4*k4+3][j4r];
        acc.x -= kv.x*n0.x + kv.y*n1.x + kv.z*n2.x + kv.w*n3.x;
        acc.y -= kv.x*n0.y + kv.y*n1.y + kv.z*n2.y + kv.w*n3.y;
        acc.z -= kv.x*n0.z + kv.y*n1.z + kv.z*n2.z + kv.w*n3.z;
        acc.w -= kv.x*n0.w + kv.y*n1.w + kv.z*n2.w + kv.w*n3.w;
      }
      *(float4*)&Sp2[iR][j4r] = acc;
    }
    __syncthreads();

    {
      float4 acc = make_float4(0.f,0.f,0.f,0.f);
      #pragma unroll
      for (int k4 = 0; k4 < 8; ++k4) {
        float4 av = *(const float4*)&Am[iR][k4*4];
        float4 b0 = *(const float4*)&Sp2[4*k4+0][j4r];
        float4 b1 = *(const float4*)&Sp2[4*k4+1][j4r];
        float4 b2 = *(const float4*)&Sp2[4*k4+2][j4r];
        float4 b3 = *(const float4*)&Sp2[4*k4+3][j4r];
        acc.x += av.x*b0.x + av.y*b1.x + av.z*b2.x + av.w*b3.x;
        acc.y += av.x*b0.y + av.y*b1.y + av.z*b2.y + av.w*b3.y;
        acc.z += av.x*b0.z + av.y*b1.z + av.z*b2.z + av.w*b3.z;
        acc.w += av.x*b0.w + av.y*b1.w + av.z*b2.w + av.w*b3.w;
      }
      *(float4*)&T2m[iR][j4r] = acc;
    }
    __syncthreads();

    {
      float4 acc = make_float4(0.f,0.f,0.f,0.f);
      #pragma unroll
      for (int k4 = 0; k4 < 8; ++k4) {
        float4 tv = *(const float4*)&T2m[iR][k4*4];
        float4 b0 = *(const float4*)&AmT[4*k4+0][j4r];
        float4 b1 = *(const float4*)&AmT[4*k4+1][j4r];
        float4 b2 = *(const float4*)&AmT[4*k4+2][j4r];
        float4 b3 = *(const float4*)&AmT[4*k4+3][j4r];
        acc.x += tv.x*b0.x + tv.y*b1.x + tv.z*b2.x + tv.w*b3.x;
        acc.y += tv.x*b0.y + tv.y*b1.y + tv.z*b2.y + tv.w*b3.y;
        acc.z += tv.x*b0.z + tv.y*b1.z + tv.z*b2.z + tv.w*b3.z;
        acc.w += tv.x*b0.w + tv.y*b1.w + tv.z*b2.w + tv.w*b3.w;
      }
      int d = iR - j4r;
      if (d >= 0 && d < 4) (&acc.x)[d] += 0.01f;
      *(float4*)&Sg[iR][j4r] = acc;
    }
    if (tid < DZ) {
      float m = 0.0f;
      #pragma unroll
      for (int k4 = 0; k4 < 8; ++k4)
        m += dot4(*(const float4*)&Am[tid][k4*4], *(const float4*)&mun[k4*4]);
      muv[tid] = m;
    }
    __syncthreads();
  }
}

extern "C" void kernel_launch(void* const* d_in, const int* in_sizes, int n_in,
                              void* d_out, int out_size, void* d_ws, size_t ws_size,
                              hipStream_t stream) {
  const float* a    = (const float*)d_in[0];
  const float* A    = (const float*)d_in[1];
  const float* C    = (const float*)d_in[2];
  const float* a0   = (const float*)d_in[3];
  const float* Wih0 = (const float*)d_in[4];
  const float* Whh0 = (const float*)d_in[5];
  const float* bih0 = (const float*)d_in[6];
  const float* bhh0 = (const float*)d_in[7];
  const float* Wih1 = (const float*)d_in[8];
  const float* Whh1 = (const float*)d_in[9];
  const float* bih1 = (const float*)d_in[10];
  const float* bhh1 = (const float*)d_in[11];
  const float* Wlin = (const float*)d_in[12];
  const float* blin = (const float*)d_in[13];
  uint32_t* ws = (uint32_t*)d_ws;
  float* alpha = (float*)(ws + 103424);
  float* out = (float*)d_out;

  prep_kernel<<<404, 256, 0, stream>>>(Wih0, Whh0, bih0, bhh0, Wih1, Whh1, bih1, bhh1, ws);
  lstm_kernel<<<512, 512, 0, stream>>>(a, a0, ws, Wlin, blin, alpha);
  kalman_kernel<<<512, 256, 0, stream>>>(a, A, C, alpha, out);
}

// Round 10
// 1255.666 us; speedup vs baseline: 1.2210x; 1.2210x over previous
//
#include <hip/hip_runtime.h>
#include <hip/hip_fp16.h>
#include <cstdint>

#define T_LEN 128
#define DA    16
#define DZ    32
#define HH    128

__device__ __forceinline__ float sigm(float x){ return 1.0f/(1.0f + __expf(-x)); }
__device__ __forceinline__ float tanh_f(float x){ return 1.0f - 2.0f/(__expf(2.0f*x)+1.0f); }
__device__ __forceinline__ float dot4(float4 a, float4 b){ return a.x*b.x + a.y*b.y + a.z*b.z + a.w*b.w; }

typedef _Float16 h2v __attribute__((ext_vector_type(2)));
__device__ __forceinline__ float fdot2(uint32_t w, uint32_t h, float acc){
  union{uint32_t u; h2v v;} a, b; a.u = w; b.u = h;
  return __builtin_amdgcn_fdot2(a.v, b.v, acc, false);
}
__device__ __forceinline__ uint32_t packh2(float x, float y){
  return (uint32_t)__half_as_ushort(__float2half(x)) |
         ((uint32_t)__half_as_ushort(__float2half(y)) << 16);
}

// ws layout (32-bit words):
//   [0,4096)         Wih0h fp16-pairs: word idx (m*512+g)*4+q, m<2, q<4 -> w[g][8m+2q..+1]
//   [4096,36864)     Whh0h: m<16
//   [36864,69632)    Wih1h: m<16
//   [69632,102400)   Whh1h: m<16
//   [102400,102912)  b0 = bih0+bhh0 (f32)
//   [102912,103424)  b1 = bih1+bhh1 (f32)
//   [103424,300032)  alpha (512,128,3) f32

__global__ void prep_kernel(const float* __restrict__ Wih0, const float* __restrict__ Whh0,
                            const float* __restrict__ bih0, const float* __restrict__ bhh0,
                            const float* __restrict__ Wih1, const float* __restrict__ Whh1,
                            const float* __restrict__ bih1, const float* __restrict__ bhh1,
                            uint32_t* __restrict__ ws) {
  int idx = blockIdx.x*256 + threadIdx.x;
  if (idx < 4096) {
    int q = idx & 3, g = (idx >> 2) & 511, m = idx >> 11;
    int k0 = 8*m + 2*q;
    ws[idx] = packh2(Wih0[g*DA + k0], Wih0[g*DA + k0 + 1]);
  } else if (idx < 36864) {
    int f = idx - 4096;
    int q = f & 3, g = (f >> 2) & 511, m = f >> 11;
    int k0 = 8*m + 2*q;
    ws[idx] = packh2(Whh0[g*HH + k0], Whh0[g*HH + k0 + 1]);
  } else if (idx < 69632) {
    int f = idx - 36864;
    int q = f & 3, g = (f >> 2) & 511, m = f >> 11;
    int k0 = 8*m + 2*q;
    ws[idx] = packh2(Wih1[g*HH + k0], Wih1[g*HH + k0 + 1]);
  } else if (idx < 102400) {
    int f = idx - 69632;
    int q = f & 3, g = (f >> 2) & 511, m = f >> 11;
    int k0 = 8*m + 2*q;
    ws[idx] = packh2(Whh1[g*HH + k0], Whh1[g*HH + k0 + 1]);
  } else if (idx < 102912) {
    int j = idx - 102400;
    ((float*)ws)[idx] = bih0[j] + bhh0[j];
  } else if (idx < 103424) {
    int j = idx - 102912;
    ((float*)ws)[idx] = bih1[j] + bhh1[j];
  }
}

// Persistent 2-layer LSTM v10 = r8 (register-resident weights) + r6 (dual-row).
// 256 blocks x 512 threads x 2 rows: thread g holds all its weight rows in
// VGPRs (200) and accumulates gate g for BOTH batch rows, so each h-broadcast
// ds_read_b128 (the r8 bottleneck: LDS return BW) is amortized over 2 rows.
// Per CU: 1 block, 8 waves x 104 b128 x ~12cyc ~= 10K cyc per step per 2 rows.
// Head: wave r(<2) reduces row r's logits from registers via shfl - no extra
// barriers (4/step). Act threads (tid<128): wave wv handles row wv, cells
// 2*lane, 2*lane+1; cell state in their registers.
__global__ __launch_bounds__(512, 2) void lstm_kernel(
    const float* __restrict__ a, const float* __restrict__ a0,
    const uint32_t* __restrict__ wsw, const float* __restrict__ Wlin,
    const float* __restrict__ blin, float* __restrict__ alpha_out) {
  const uint4* Wih0p = (const uint4*)(wsw);
  const uint4* Whh0p = (const uint4*)(wsw + 4096);
  const uint4* Wih1p = (const uint4*)(wsw + 36864);
  const uint4* Whh1p = (const uint4*)(wsw + 69632);
  const float* b0v = (const float*)(wsw + 102400);
  const float* b1v = (const float*)(wsw + 102912);

  __shared__ __align__(16) uint32_t sxh[2][T_LEN][8];  // x packed half2, 2 rows
  __shared__ __align__(16) uint32_t sh0h[2][64];       // h0 packed half2
  __shared__ __align__(16) uint32_t sh1h[2][64];       // h1 packed half2
  __shared__ float gates[2][4*HH];

  int tid = threadIdx.x;
  int lane = tid & 63;
  int wv = tid >> 6;
  int bb = blockIdx.x * 2;

  // ---- one-time: weights into registers ----
  uint4 wi0[2], wh0[16], wi1[16], wh1[16];
  #pragma unroll
  for (int m = 0; m < 2; ++m)  wi0[m] = Wih0p[m*512 + tid];
  #pragma unroll
  for (int m = 0; m < 16; ++m) wh0[m] = Whh0p[m*512 + tid];
  #pragma unroll
  for (int m = 0; m < 16; ++m) wi1[m] = Wih1p[m*512 + tid];
  #pragma unroll
  for (int m = 0; m < 16; ++m) wh1[m] = Whh1p[m*512 + tid];
  float bi0 = b0v[tid], bi1 = b1v[tid];

  for (int i = tid; i < 2*T_LEN*8; i += 512) {
    int r = i / (T_LEN*8), rem = i % (T_LEN*8), t = rem >> 3, p = rem & 7;
    float x0, x1;
    if (t == 0) { x0 = a0[2*p]; x1 = a0[2*p+1]; }
    else {
      const float* src = a + ((size_t)(bb + r)*T_LEN + (t-1))*DA;
      x0 = src[2*p]; x1 = src[2*p+1];
    }
    sxh[r][t][p] = packh2(x0, x1);
  }
  // head weights per lane (only waves 0-1 use them)
  float wl00 = Wlin[0*HH + 2*lane], wl01 = Wlin[0*HH + 2*lane+1];
  float wl10 = Wlin[1*HH + 2*lane], wl11 = Wlin[1*HH + 2*lane+1];
  float wl20 = Wlin[2*HH + 2*lane], wl21 = Wlin[2*HH + 2*lane+1];
  float bl0 = blin[0], bl1 = blin[1], bl2 = blin[2];
  // cell states for act threads (tid<128): row wv, cells 2*lane, 2*lane+1
  float c00 = 0.f, c01 = 0.f, c10 = 0.f, c11 = 0.f;
  if (tid < 128) { sh0h[wv][lane] = 0u; sh1h[wv][lane] = 0u; }
  __syncthreads();

  #pragma unroll 1
  for (int t = 0; t < T_LEN; ++t) {
    // ---- layer 0 gates: g = tid, rows 0..1 ----
    {
      float g0a = bi0, g0b = 0.f, g1a = bi0, g1b = 0.f;
      uint4 xA0 = *(const uint4*)&sxh[0][t][0];
      uint4 xA1 = *(const uint4*)&sxh[0][t][4];
      uint4 xB0 = *(const uint4*)&sxh[1][t][0];
      uint4 xB1 = *(const uint4*)&sxh[1][t][4];
      g0a = fdot2(wi0[0].x, xA0.x, g0a); g0b = fdot2(wi0[0].y, xA0.y, g0b);
      g0a = fdot2(wi0[0].z, xA0.z, g0a); g0b = fdot2(wi0[0].w, xA0.w, g0b);
      g0a = fdot2(wi0[1].x, xA1.x, g0a); g0b = fdot2(wi0[1].y, xA1.y, g0b);
      g0a = fdot2(wi0[1].z, xA1.z, g0a); g0b = fdot2(wi0[1].w, xA1.w, g0b);
      g1a = fdot2(wi0[0].x, xB0.x, g1a); g1b = fdot2(wi0[0].y, xB0.y, g1b);
      g1a = fdot2(wi0[0].z, xB0.z, g1a); g1b = fdot2(wi0[0].w, xB0.w, g1b);
      g1a = fdot2(wi0[1].x, xB1.x, g1a); g1b = fdot2(wi0[1].y, xB1.y, g1b);
      g1a = fdot2(wi0[1].z, xB1.z, g1a); g1b = fdot2(wi0[1].w, xB1.w, g1b);
      #pragma unroll
      for (int m = 0; m < 16; ++m) {
        uint4 w = wh0[m];
        uint4 hA = *(const uint4*)&sh0h[0][4*m];
        uint4 hB = *(const uint4*)&sh0h[1][4*m];
        g0a = fdot2(w.x, hA.x, g0a); g0b = fdot2(w.y, hA.y, g0b);
        g0a = fdot2(w.z, hA.z, g0a); g0b = fdot2(w.w, hA.w, g0b);
        g1a = fdot2(w.x, hB.x, g1a); g1b = fdot2(w.y, hB.y, g1b);
        g1a = fdot2(w.z, hB.z, g1a); g1b = fdot2(w.w, hB.w, g1b);
      }
      gates[0][tid] = g0a + g0b;
      gates[1][tid] = g1a + g1b;
    }
    __syncthreads();                                   // B1
    if (tid < 128) {
      int j0 = 2*lane, j1 = j0 + 1;
      float i0 = gates[wv][j0],      f0 = gates[wv][j0+HH],
            q0 = gates[wv][j0+2*HH], o0 = gates[wv][j0+3*HH];
      c00 = sigm(f0)*c00 + sigm(i0)*tanh_f(q0);
      float hv0 = sigm(o0)*tanh_f(c00);
      float i1 = gates[wv][j1],      f1 = gates[wv][j1+HH],
            q1 = gates[wv][j1+2*HH], o1 = gates[wv][j1+3*HH];
      c01 = sigm(f1)*c01 + sigm(i1)*tanh_f(q1);
      float hv1 = sigm(o1)*tanh_f(c01);
      sh0h[wv][lane] = packh2(hv0, hv1);
    }
    __syncthreads();                                   // B2
    // ---- layer 1 gates ----
    {
      float g0a = bi1, g0b = 0.f, g1a = bi1, g1b = 0.f;
      #pragma unroll
      for (int m = 0; m < 16; ++m) {
        uint4 w = wi1[m];
        uint4 hA = *(const uint4*)&sh0h[0][4*m];
        uint4 hB = *(const uint4*)&sh0h[1][4*m];
        g0a = fdot2(w.x, hA.x, g0a); g0b = fdot2(w.y, hA.y, g0b);
        g0a = fdot2(w.z, hA.z, g0a); g0b = fdot2(w.w, hA.w, g0b);
        g1a = fdot2(w.x, hB.x, g1a); g1b = fdot2(w.y, hB.y, g1b);
        g1a = fdot2(w.z, hB.z, g1a); g1b = fdot2(w.w, hB.w, g1b);
      }
      #pragma unroll
      for (int m = 0; m < 16; ++m) {
        uint4 w = wh1[m];
        uint4 hA = *(const uint4*)&sh1h[0][4*m];
        uint4 hB = *(const uint4*)&sh1h[1][4*m];
        g0a = fdot2(w.x, hA.x, g0a); g0b = fdot2(w.y, hA.y, g0b);
        g0a = fdot2(w.z, hA.z, g0a); g0b = fdot2(w.w, hA.w, g0b);
        g1a = fdot2(w.x, hB.x, g1a); g1b = fdot2(w.y, hB.y, g1b);
        g1a = fdot2(w.z, hB.z, g1a); g1b = fdot2(w.w, hB.w, g1b);
      }
      gates[0][tid] = g0a + g0b;
      gates[1][tid] = g1a + g1b;
    }
    __syncthreads();                                   // B3
    float hv0 = 0.f, hv1 = 0.f;
    if (tid < 128) {
      int j0 = 2*lane, j1 = j0 + 1;
      float i0 = gates[wv][j0],      f0 = gates[wv][j0+HH],
            q0 = gates[wv][j0+2*HH], o0 = gates[wv][j0+3*HH];
      c10 = sigm(f0)*c10 + sigm(i0)*tanh_f(q0);
      hv0 = sigm(o0)*tanh_f(c10);
      float i1 = gates[wv][j1],      f1 = gates[wv][j1+HH],
            q1 = gates[wv][j1+2*HH], o1 = gates[wv][j1+3*HH];
      c11 = sigm(f1)*c11 + sigm(i1)*tanh_f(q1);
      hv1 = sigm(o1)*tanh_f(c11);
      sh1h[wv][lane] = packh2(hv0, hv1);
    }
    __syncthreads();                                   // B4
    // ---- head: wave r (<2) reduces row r's logits from registers ----
    if (tid < 128) {
      float p0 = hv0*wl00 + hv1*wl01;
      float p1 = hv0*wl10 + hv1*wl11;
      float p2 = hv0*wl20 + hv1*wl21;
      #pragma unroll
      for (int off = 32; off > 0; off >>= 1) {
        p0 += __shfl_down(p0, off); p1 += __shfl_down(p1, off); p2 += __shfl_down(p2, off);
      }
      if (lane == 0) {
        float l0 = p0 + bl0, l1 = p1 + bl1, l2 = p2 + bl2;
        float mx = fmaxf(l0, fmaxf(l1, l2));
        float e0=__expf(l0-mx), e1=__expf(l1-mx), e2=__expf(l2-mx);
        float inv = 1.0f/(e0+e1+e2);
        float* dst = alpha_out + (((size_t)(bb+wv))*T_LEN + t)*3;
        dst[0]=e0*inv; dst[1]=e1*inv; dst[2]=e2*inv;
      }
    }
    // no 5th barrier: next writers (gates at B1-region of t+1, sh0h/sh1h behind
    // B1..B3 of t+1) are ordered after B4; head used registers only.
  }
}

// Kalman scan v4 (bit-identical to round 8): conflict-free k-row matmuls,
// register prefetch of A/C, wave-synchronous Gauss-Jordan.
__global__ __launch_bounds__(256) void kalman_kernel(
    const float* __restrict__ a, const float* __restrict__ A,
    const float* __restrict__ C, const float* __restrict__ alpha,
    float* __restrict__ out) {
  __shared__ __align__(16) float Sg[DZ][36];
  __shared__ __align__(16) float Am[DZ][36];
  __shared__ __align__(16) float AmT[DZ][36];
  __shared__ __align__(16) float Cm[DA][36];
  __shared__ __align__(16) float Nn[DZ][20];
  __shared__ __align__(16) float NnT[DA][36];
  __shared__ __align__(16) float Aug[DA][36];
  __shared__ __align__(16) float Kg[DZ][20];
  __shared__ __align__(16) float Sp2[DZ][36];
  __shared__ __align__(16) float T2m[DZ][36];
  __shared__ __align__(16) float sa[T_LEN][DA];
  __shared__ float salpha[T_LEN*3];
  __shared__ __align__(16) float muv[DZ], mun[DZ], rv[DA];

  int tid = threadIdx.x;
  int b = blockIdx.x;

  for (int e = tid; e < T_LEN*DA; e += 256) (&sa[0][0])[e] = a[(size_t)b*T_LEN*DA + e];
  for (int e = tid; e < T_LEN*3; e += 256) salpha[e] = alpha[(size_t)b*T_LEN*3 + e];
  for (int e = tid; e < DZ*36; e += 256) (&Sg[0][0])[e] = 0.0f;
  __syncthreads();
  if (tid < DZ) { Sg[tid][tid] = 1.0f; muv[tid] = 0.0f; }

  const int i8 = tid >> 3, jA = tid & 7, jB = jA + 8, j4m = jA * 4;
  const int i16 = tid >> 4, j16 = tid & 15;
  const int iR = tid & 31, j4r = (tid >> 5) * 4;

  const float4* A4 = (const float4*)A;
  const float4* C4 = (const float4*)C;
  float4 pA0 = A4[(0*T_LEN + 1)*256 + tid];
  float4 pA1 = A4[(1*T_LEN + 1)*256 + tid];
  float4 pA2 = A4[(2*T_LEN + 1)*256 + tid];
  float4 pC0, pC1, pC2;
  if (tid < 128) {
    pC0 = C4[(0*T_LEN + 0)*128 + tid];
    pC1 = C4[(1*T_LEN + 0)*128 + tid];
    pC2 = C4[(2*T_LEN + 0)*128 + tid];
  }
  __syncthreads();

  #pragma unroll 1
  for (int t = 0; t < T_LEN; ++t) {
    int ta = (t < T_LEN-1) ? t+1 : t;
    float b10 = salpha[ta*3+0], b11 = salpha[ta*3+1], b12 = salpha[ta*3+2];
    float b00 = salpha[t*3+0],  b01 = salpha[t*3+1],  b02 = salpha[t*3+2];

    {
      float4 v;
      v.x = b10*pA0.x + b11*pA1.x + b12*pA2.x;
      v.y = b10*pA0.y + b11*pA1.y + b12*pA2.y;
      v.z = b10*pA0.z + b11*pA1.z + b12*pA2.z;
      v.w = b10*pA0.w + b11*pA1.w + b12*pA2.w;
      *(float4*)&Am[i8][j4m] = v;
      AmT[j4m+0][i8] = v.x; AmT[j4m+1][i8] = v.y;
      AmT[j4m+2][i8] = v.z; AmT[j4m+3][i8] = v.w;
      if (tid < 128) {
        float4 c;
        c.x = b00*pC0.x + b01*pC1.x + b02*pC2.x;
        c.y = b00*pC0.y + b01*pC1.y + b02*pC2.y;
        c.z = b00*pC0.z + b01*pC1.z + b02*pC2.z;
        c.w = b00*pC0.w + b01*pC1.w + b02*pC2.w;
        *(float4*)&Cm[tid>>3][(tid&7)*4] = c;
      }
      int tn  = (t+1 < T_LEN) ? t+1 : T_LEN-1;
      int tan = (tn < T_LEN-1) ? tn+1 : tn;
      pA0 = A4[(0*T_LEN + tan)*256 + tid];
      pA1 = A4[(1*T_LEN + tan)*256 + tid];
      pA2 = A4[(2*T_LEN + tan)*256 + tid];
      if (tid < 128) {
        pC0 = C4[(0*T_LEN + tn)*128 + tid];
        pC1 = C4[(1*T_LEN + tn)*128 + tid];
        pC2 = C4[(2*T_LEN + tn)*128 + tid];
      }
    }
    __syncthreads();

    {
      float accA = 0.0f, accB = 0.0f;
      #pragma unroll
      for (int k4 = 0; k4 < 8; ++k4) {
        float4 s  = *(const float4*)&Sg[i8][k4*4];
        float4 cA = *(const float4*)&Cm[jA][k4*4];
        float4 cB = *(const float4*)&Cm[jB][k4*4];
        accA += dot4(s,cA); accB += dot4(s,cB);
      }
      Nn[i8][jA] = accA; Nn[i8][jB] = accB;
      NnT[jA][i8] = accA; NnT[jB][i8] = accB;
      if (tid < DA) {
        float acc = sa[t][tid];
        #pragma unroll
        for (int k4 = 0; k4 < 8; ++k4)
          acc -= dot4(*(const float4*)&Cm[tid][k4*4], *(const float4*)&muv[k4*4]);
        rv[tid] = acc;
      }
    }
    __syncthreads();

    {
      float acc = 0.0f;
      #pragma unroll
      for (int k4 = 0; k4 < 8; ++k4) {
        float4 c = *(const float4*)&Cm[i16][k4*4];
        float4 n = *(const float4*)&NnT[j16][k4*4];
        acc += dot4(c,n);
      }
      Aug[i16][j16] = acc + ((i16 == j16) ? 0.01f : 0.0f);
      Aug[i16][16 + j16] = (i16 == j16) ? 1.0f : 0.0f;
    }
    __syncthreads();

    if (tid < 64) {
      int lane = tid;
      int r = lane >> 2, cb = lane & 3;
      float v[8];
      #pragma unroll
      for (int j = 0; j < 8; ++j) v[j] = Aug[r][cb*8 + j];
      #pragma unroll
      for (int p = 0; p < DA; ++p) {
        float App = __shfl(v[p & 7], (p << 2) | (p >> 3), 64);
        float f   = __shfl(v[p & 7], (lane & 60) | (p >> 3), 64);
        float prow[8];
        #pragma unroll
        for (int j = 0; j < 8; ++j) prow[j] = __shfl(v[j], (p << 2) | cb, 64);
        float pinv = 1.0f / App;
        if (r == p) {
          #pragma unroll
          for (int j = 0; j < 8; ++j) v[j] *= pinv;
        } else {
          float fp = f * pinv;
          #pragma unroll
          for (int j = 0; j < 8; ++j) v[j] -= fp * prow[j];
        }
      }
      if (cb >= 2) {
        #pragma unroll
        for (int j = 0; j < 8; ++j) Aug[r][cb*8 + j] = v[j];
      }
    }
    __syncthreads();

    {
      float accA = 0.0f, accB = 0.0f;
      #pragma unroll
      for (int k4 = 0; k4 < 4; ++k4) {
        float4 n  = *(const float4*)&Nn[i8][k4*4];
        float4 sA = *(const float4*)&Aug[jA][16 + k4*4];
        float4 sB = *(const float4*)&Aug[jB][16 + k4*4];
        accA += dot4(n,sA); accB += dot4(n,sB);
      }
      Kg[i8][jA] = accA; Kg[i8][jB] = accB;
    }
    __syncthreads();

    if (tid < DZ) {
      float m = muv[tid];
      #pragma unroll
      for (int k4 = 0; k4 < 4; ++k4)
        m += dot4(*(const float4*)&Kg[tid][k4*4], *(const float4*)&rv[k4*4]);
      mun[tid] = m;
      out[((size_t)b*T_LEN + t)*DZ + tid] = m;
    }
    {
      float4 acc = *(const float4*)&Sg[iR][j4r];
      #pragma unroll
      for (int k4 = 0; k4 < 4; ++k4) {
        float4 kv = *(const float4*)&Kg[iR][k4*4];
        float4 n0 = *(const float4*)&NnT[4*k4+0][j4r];
        float4 n1 = *(const float4*)&NnT[4*k4+1][j4r];
        float4 n2 = *(const float4*)&NnT[4*k4+2][j4r];
        float4 n3 = *(const float4*)&NnT[4*k4+3][j4r];
        acc.x -= kv.x*n0.x + kv.y*n1.x + kv.z*n2.x + kv.w*n3.x;
        acc.y -= kv.x*n0.y + kv.y*n1.y + kv.z*n2.y + kv.w*n3.y;
        acc.z -= kv.x*n0.z + kv.y*n1.z + kv.z*n2.z + kv.w*n3.z;
        acc.w -= kv.x*n0.w + kv.y*n1.w + kv.z*n2.w + kv.w*n3.w;
      }
      *(float4*)&Sp2[iR][j4r] = acc;
    }
    __syncthreads();

    {
      float4 acc = make_float4(0.f,0.f,0.f,0.f);
      #pragma unroll
      for (int k4 = 0; k4 < 8; ++k4) {
        float4 av = *(const float4*)&Am[iR][k4*4];
        float4 b0 = *(const float4*)&Sp2[4*k4+0][j4r];
        float4 b1 = *(const float4*)&Sp2[4*k4+1][j4r];
        float4 b2 = *(const float4*)&Sp2[4*k4+2][j4r];
        float4 b3 = *(const float4*)&Sp2[4*k4+3][j4r];
        acc.x += av.x*b0.x + av.y*b1.x + av.z*b2.x + av.w*b3.x;
        acc.y += av.x*b0.y + av.y*b1.y + av.z*b2.y + av.w*b3.y;
        acc.z += av.x*b0.z + av.y*b1.z + av.z*b2.z + av.w*b3.z;
        acc.w += av.x*b0.w + av.y*b1.w + av.z*b2.w + av.w*b3.w;
      }
      *(float4*)&T2m[iR][j4r] = acc;
    }
    __syncthreads();

    {
      float4 acc = make_float4(0.f,0.f,0.f,0.f);
      #pragma unroll
      for (int k4 = 0; k4 < 8; ++k4) {
        float4 tv = *(const float4*)&T2m[iR][k4*4];
        float4 b0 = *(const float4*)&AmT[4*k4+0][j4r];
        float4 b1 = *(const float4*)&AmT[4*k4+1][j4r];
        float4 b2 = *(const float4*)&AmT[4*k4+2][j4r];
        float4 b3 = *(const float4*)&AmT[4*k4+3][j4r];
        acc.x += tv.x*b0.x + tv.y*b1.x + tv.z*b2.x + tv.w*b3.x;
        acc.y += tv.x*b0.y + tv.y*b1.y + tv.z*b2.y + tv.w*b3.y;
        acc.z += tv.x*b0.z + tv.y*b1.z + tv.z*b2.z + tv.w*b3.z;
        acc.w += tv.x*b0.w + tv.y*b1.w + tv.z*b2.w + tv.w*b3.w;
      }
      int d = iR - j4r;
      if (d >= 0 && d < 4) (&acc.x)[d] += 0.01f;
      *(float4*)&Sg[iR][j4r] = acc;
    }
    if (tid < DZ) {
      float m = 0.0f;
      #pragma unroll
      for (int k4 = 0; k4 < 8; ++k4)
        m += dot4(*(const float4*)&Am[tid][k4*4], *(const float4*)&mun[k4*4]);
      muv[tid] = m;
    }
    __syncthreads();
  }
}

extern "C" void kernel_launch(void* const* d_in, const int* in_sizes, int n_in,
                              void* d_out, int out_size, void* d_ws, size_t ws_size,
                              hipStream_t stream) {
  const float* a    = (const float*)d_in[0];
  const float* A    = (const float*)d_in[1];
  const float* C    = (const float*)d_in[2];
  const float* a0   = (const float*)d_in[3];
  const float* Wih0 = (const float*)d_in[4];
  const float* Whh0 = (const float*)d_in[5];
  const float* bih0 = (const float*)d_in[6];
  const float* bhh0 = (const float*)d_in[7];
  const float* Wih1 = (const float*)d_in[8];
  const float* Whh1 = (const float*)d_in[9];
  const float* bih1 = (const float*)d_in[10];
  const float* bhh1 = (const float*)d_in[11];
  const float* Wlin = (const float*)d_in[12];
  const float* blin = (const float*)d_in[13];
  uint32_t* ws = (uint32_t*)d_ws;
  float* alpha = (float*)(ws + 103424);
  float* out = (float*)d_out;

  prep_kernel<<<404, 256, 0, stream>>>(Wih0, Whh0, bih0, bhh0, Wih1, Whh1, bih1, bhh1, ws);
  lstm_kernel<<<256, 512, 0, stream>>>(a, a0, ws, Wlin, blin, alpha);
  kalman_kernel<<<512, 256, 0, stream>>>(a, A, C, alpha, out);
}